// Round 20
// baseline (47.704 us; speedup 1.0000x reference)
//
#include <hip/hip_runtime.h>
#include <math.h>

// ---- problem constants ----
#define B_N    2
#define S_LEN  2048
#define DMODEL 192
#define LOG2E  1.44269504088896340736f
#define FMAXL2 12.0f   // fixed softmax max (log2 domain); scores bounded << this

typedef __attribute__((ext_vector_type(8)))  short bf16x8;
typedef __attribute__((ext_vector_type(4)))  float f32x4;
typedef __attribute__((ext_vector_type(16))) float f32x16;

static __device__ __forceinline__ unsigned short f2bf(float f) {
    union { float f; unsigned u; } v; v.f = f;
    unsigned r = v.u + 0x7FFFu + ((v.u >> 16) & 1u);
    return (unsigned short)(r >> 16);
}
static __device__ __forceinline__ unsigned pk2(float a, float b) {
    return (unsigned)f2bf(a) | ((unsigned)f2bf(b) << 16);
}
static __device__ __forceinline__ unsigned cvtpk_bf16(float a, float b) {
    unsigned r;
    asm("v_cvt_pk_bf16_f32 %0, %1, %2" : "=v"(r) : "v"(a), "v"(b));
    return r;
}

// Fragment-major layouts (all attn reads are base + lane*16B, 1KB/instr):
//  Kf [b][kvh][t][f:2][lane:64][8]  lane = key&31 | ((d>>3)&1)<<5, f = d>>4
//  Phf[b]     [t][f:8][lane:64][8]  lane = key&31 | ((d>>3)&1)<<5, f = d>>4
//  Vf [b][kvh][t][f:2][lane:64][8]  lane = d     | ((kr>>3)&1)<<5, f = kr>>4

// ============================================================
// K1: prep — R19-verbatim.  Launched TWICE this round
// (idempotent) — dur delta vs R19 measures prep + one gap.
// ============================================================
__global__ __launch_bounds__(256) void prep_kernel(
    const float* __restrict__ x, const float* __restrict__ Wq,
    const float* __restrict__ Wkv, const float* __restrict__ alpha_p,
    const float* __restrict__ beta_p,
    unsigned short* __restrict__ Qh, unsigned short* __restrict__ Kf,
    unsigned short* __restrict__ Phq, unsigned short* __restrict__ Phf,
    unsigned short* __restrict__ Vf)
{
    __shared__ __align__(16) unsigned short a_lds[64][200];
    __shared__ __align__(16) unsigned short b_lds[64][200];
    const int blk = blockIdx.x, tid = threadIdx.x;

    if (blk < 384) {
        const int wid = tid >> 6, lane = tid & 63, g = lane >> 4, lr = lane & 15;
        const int brow = (blk & 63) * 64;
        const int bcol = (blk >> 6) * 64;

        #pragma unroll
        for (int c = 0; c < 12; ++c) {
            int idx = c * 256 + tid;
            int r = idx / 48, ch = idx % 48;
            float4 v = *(const float4*)&x[(size_t)(brow + r) * 192 + ch * 4];
            uint2 w; w.x = pk2(v.x, v.y); w.y = pk2(v.z, v.w);
            *(uint2*)&a_lds[r][ch * 4] = w;
            int wr = bcol + r;
            const float* wsrc = (wr < 192) ? &Wq[(size_t)wr * 192 + ch * 4]
                                           : &Wkv[(size_t)(wr - 192) * 192 + ch * 4];
            float4 wv = *(const float4*)wsrc;
            uint2 w2; w2.x = pk2(wv.x, wv.y); w2.y = pk2(wv.z, wv.w);
            *(uint2*)&b_lds[r][ch * 4] = w2;
        }
        __syncthreads();

        f32x4 acc[4];
        #pragma unroll
        for (int nc = 0; nc < 4; ++nc) acc[nc] = (f32x4){0.f, 0.f, 0.f, 0.f};
        #pragma unroll
        for (int kc = 0; kc < 6; ++kc) {
            bf16x8 af = *(const bf16x8*)&a_lds[wid * 16 + lr][kc * 32 + g * 8];
            #pragma unroll
            for (int nc = 0; nc < 4; ++nc) {
                bf16x8 bfr = *(const bf16x8*)&b_lds[nc * 16 + lr][kc * 32 + g * 8];
                acc[nc] = __builtin_amdgcn_mfma_f32_16x16x32_bf16(af, bfr, acc[nc], 0, 0, 0);
            }
        }

        const float qs = alpha_p[0] * 0.20412414523193150818f * LOG2E;
        const float scale = (bcol < 192) ? qs : 1.0f;
        __syncthreads();
        unsigned short (*sm)[80] = (unsigned short (*)[80])&a_lds[0][0];
        #pragma unroll
        for (int nc = 0; nc < 4; ++nc)
            #pragma unroll
            for (int rr = 0; rr < 4; ++rr)
                sm[wid * 16 + g * 4 + rr][nc * 16 + lr] = f2bf(acc[nc][rr] * scale);
        __syncthreads();

        #pragma unroll
        for (int pass = 0; pass < 2; ++pass) {
            const int sp = pass * 256 + tid;
            if (bcol < 256) {
                const int cs = sp >> 6, row = sp & 63;
                const int grow = brow + row, b = grow >> 11, s = grow & 2047;
                uint4 v = *(const uint4*)&sm[row][cs * 8];
                const int col = bcol + cs * 8;
                if (bcol < 192) {
                    int h = col / 24, d = col - 24 * h;
                    *(uint4*)(Qh + ((size_t)(b * 8 + h) * S_LEN + s) * 32 + d) = v;
                } else {
                    int cc = col - 192, kvh = cc / 24, d = cc - 24 * kvh;
                    int t = s >> 5, kr = s & 31;
                    *(uint4*)(Kf + (((size_t)(b * 4 + kvh) * 64 + t) * 2 + (d >> 4)) * 512
                              + (kr + 32 * ((d >> 3) & 1)) * 8) = v;
                }
            } else if (bcol == 256) {
                if (sp < 256) {
                    const int cs = sp >> 6, row = sp & 63;
                    const int grow = brow + row, b = grow >> 11, s = grow & 2047;
                    uint4 v = *(const uint4*)&sm[row][cs * 8];
                    const int col = 256 + cs * 8;
                    int cc = col - 192, kvh = cc / 24, d = cc - 24 * kvh;
                    int t = s >> 5, kr = s & 31;
                    *(uint4*)(Kf + (((size_t)(b * 4 + kvh) * 64 + t) * 2 + (d >> 4)) * 512
                              + (kr + 32 * ((d >> 3) & 1)) * 8) = v;
                } else {
                    const int sp2 = sp - 256;
                    const int colL = 32 + (sp2 & 31), r0 = (sp2 >> 5) * 8;
                    const int grow0 = brow + r0, b = grow0 >> 11, s0 = grow0 & 2047;
                    const int col = 256 + colL;
                    int cc = col - 288, kvh = cc / 24, d = cc - 24 * kvh;
                    int t = s0 >> 5, kr0 = s0 & 31;
                    unsigned w0 = (unsigned)sm[r0][colL]     | ((unsigned)sm[r0 + 1][colL] << 16);
                    unsigned w1 = (unsigned)sm[r0 + 2][colL] | ((unsigned)sm[r0 + 3][colL] << 16);
                    unsigned w2 = (unsigned)sm[r0 + 4][colL] | ((unsigned)sm[r0 + 5][colL] << 16);
                    unsigned w3 = (unsigned)sm[r0 + 6][colL] | ((unsigned)sm[r0 + 7][colL] << 16);
                    uint4 v = {w0, w1, w2, w3};
                    *(uint4*)(Vf + (((size_t)(b * 4 + kvh) * 64 + t) * 2 + (kr0 >> 4)) * 512
                              + (d + 32 * ((kr0 >> 3) & 1)) * 8) = v;
                }
            } else {
                const int colL = sp & 63, r0 = (sp >> 6) * 8;
                const int grow0 = brow + r0, b = grow0 >> 11, s0 = grow0 & 2047;
                const int col = 320 + colL;
                int cc = col - 288, kvh = cc / 24, d = cc - 24 * kvh;
                int t = s0 >> 5, kr0 = s0 & 31;
                unsigned w0 = (unsigned)sm[r0][colL]     | ((unsigned)sm[r0 + 1][colL] << 16);
                unsigned w1 = (unsigned)sm[r0 + 2][colL] | ((unsigned)sm[r0 + 3][colL] << 16);
                unsigned w2 = (unsigned)sm[r0 + 4][colL] | ((unsigned)sm[r0 + 5][colL] << 16);
                unsigned w3 = (unsigned)sm[r0 + 6][colL] | ((unsigned)sm[r0 + 7][colL] << 16);
                uint4 v = {w0, w1, w2, w3};
                *(uint4*)(Vf + (((size_t)(b * 4 + kvh) * 64 + t) * 2 + (kr0 >> 4)) * 512
                          + (d + 32 * ((kr0 >> 3) & 1)) * 8) = v;
            }
        }
    } else if (blk < 896) {
        unsigned short (*psm)[128] = (unsigned short (*)[128])&a_lds[0][0];
        const int pblk = blk - 384;
        const int rr = tid >> 5, i = tid & 31;
        const int row = pblk * 8 + rr;
        const int b = row >> 11, s = row & 2047;
        const int t = s >> 5, kr = s & 31;
        const float bf = beta_p[0] * (1.0f / 64.0f) * LOG2E;
        float2 p = *(const float2*)&x[(size_t)row * DMODEL + 128 + 2 * i];
        float s0, c0, s1, c1;
        sincosf(p.x, &s0, &c0);
        sincosf(p.y, &s1, &c1);
        unsigned short* phq = Phq + ((size_t)b * S_LEN + s) * 128;
        *(unsigned*)(phq + 2 * i)      = pk2(c0 * bf, c1 * bf);
        *(unsigned*)(phq + 64 + 2 * i) = pk2(s0 * bf, s1 * bf);
        *(unsigned*)&psm[rr][2 * i]      = pk2(c0, c1);
        *(unsigned*)&psm[rr][64 + 2 * i] = pk2(s0, s1);
        if (i < 12) {
            uint4 z = {0u, 0u, 0u, 0u};
            if (i < 8) {
                *(uint4*)(Qh + ((size_t)(b * 8 + i) * S_LEN + s) * 32 + 24) = z;
            } else {
                int kvh = i - 8;
                *(uint4*)(Kf + (((size_t)(b * 4 + kvh) * 64 + t) * 2 + 1) * 512 + (kr + 32) * 8) = z;
            }
        }
        __syncthreads();
        if (tid < 128) {
            const int krow = tid & 7, d0 = (tid >> 3) * 8;
            const int grow = pblk * 8 + krow, b2 = grow >> 11, s2 = grow & 2047;
            const int t2 = s2 >> 5, kr2 = s2 & 31;
            uint4 v = *(const uint4*)&psm[krow][d0];
            *(uint4*)(Phf + (((size_t)b2 * 64 + t2) * 8 + (d0 >> 4)) * 512
                      + (kr2 + 32 * ((d0 >> 3) & 1)) * 8) = v;
        }
    } else {
        const int j = blk - 896;
        uint4 z = {0u, 0u, 0u, 0u};
        #pragma unroll
        for (int c = 0; c < 8; ++c) {
            int idx = c * 256 + tid;
            int t = idx >> 5, rem = idx & 31;
            int f = rem >> 4, dd = 24 + (rem & 7), hb = (rem >> 3) & 1;
            *(uint4*)(Vf + (((size_t)j * 64 + t) * 2 + f) * 512 + (dd + 32 * hb) * 8) = z;
        }
    }
}

// ============================================================
// K2: 4-way key-split attention — R19-verbatim.
// ============================================================
struct KB { bf16x8 kh0, kh1, ph0, ph1, ph2, ph3, ph4, ph5, ph6, ph7, vt0, vt1; };

__global__ __launch_bounds__(64, 2) void attn_kernel(
    const unsigned short* __restrict__ Qh, const unsigned short* __restrict__ Kf,
    const unsigned short* __restrict__ Phq, const unsigned short* __restrict__ Phf,
    const unsigned short* __restrict__ Vf,
    float* __restrict__ pacc, float* __restrict__ pml)
{
    const int lane = threadIdx.x & 63;
    const int hi = lane >> 5, c31 = lane & 31;

    const int bid = blockIdx.x;
    const int grp = bid & 7, b = grp >> 2, kvh = grp & 3;
    const int u = bid >> 3;
    const int quarter = u & 3;
    const int s = 63 - (u >> 2);
    const int r = s + 1;
    const int tb = (quarter * r) >> 2, te = ((quarter + 1) * r) >> 2;
    const int qrow = s * 32 + c31;

    const unsigned short* kf_g = Kf  + (size_t)(b * 4 + kvh) * 65536 + lane * 8;
    const unsigned short* ph_g = Phf + (size_t)b * 262144 + lane * 8;
    const unsigned short* vf_g = Vf  + (size_t)(b * 4 + kvh) * 65536 + lane * 8;

    f32x16 accA = {0,0,0,0,0,0,0,0,0,0,0,0,0,0,0,0};
    f32x16 accB = {0,0,0,0,0,0,0,0,0,0,0,0,0,0,0,0};
    float lA = 0.f, lB = 0.f;

    if (te > tb) {
        bf16x8 qa0, qa1, qb0, qb1, qp[8];
        {
            const unsigned short* q0 = Qh + ((size_t)(b * 8 + 2 * kvh) * S_LEN + qrow) * 32 + hi * 8;
            const unsigned short* q1 = Qh + ((size_t)(b * 8 + 2 * kvh + 1) * S_LEN + qrow) * 32 + hi * 8;
            qa0 = *(const bf16x8*)q0; qa1 = *(const bf16x8*)(q0 + 16);
            qb0 = *(const bf16x8*)q1; qb1 = *(const bf16x8*)(q1 + 16);
            const unsigned short* pq = Phq + ((size_t)b * S_LEN + qrow) * 128 + hi * 8;
            #pragma unroll
            for (int c = 0; c < 8; ++c) qp[c] = *(const bf16x8*)(pq + c * 16);
        }

        auto LOADK = [&](int t) {
            KB kb;
            const unsigned short* kg = kf_g + (size_t)t * 1024;
            const unsigned short* pg = ph_g + (size_t)t * 4096;
            const unsigned short* vg = vf_g + (size_t)t * 1024;
            kb.kh0 = *(const bf16x8*)kg;
            kb.kh1 = *(const bf16x8*)(kg + 512);
            kb.ph0 = *(const bf16x8*)pg;
            kb.ph1 = *(const bf16x8*)(pg + 512);
            kb.ph2 = *(const bf16x8*)(pg + 1024);
            kb.ph3 = *(const bf16x8*)(pg + 1536);
            kb.ph4 = *(const bf16x8*)(pg + 2048);
            kb.ph5 = *(const bf16x8*)(pg + 2560);
            kb.ph6 = *(const bf16x8*)(pg + 3072);
            kb.ph7 = *(const bf16x8*)(pg + 3584);
            kb.vt0 = *(const bf16x8*)vg;
            kb.vt1 = *(const bf16x8*)(vg + 512);
            return kb;
        };

        auto PROCESS = [&](const KB& kb, bf16x8 q0, bf16x8 q1,
                           f32x16& acc, float& l, bool diag) {
            f32x16 sa = {0,0,0,0,0,0,0,0,0,0,0,0,0,0,0,0};
            f32x16 sb = {0,0,0,0,0,0,0,0,0,0,0,0,0,0,0,0};
            sa = __builtin_amdgcn_mfma_f32_32x32x16_bf16(kb.kh0, q0, sa, 0, 0, 0);
            sb = __builtin_amdgcn_mfma_f32_32x32x16_bf16(kb.kh1, q1, sb, 0, 0, 0);
            sa = __builtin_amdgcn_mfma_f32_32x32x16_bf16(kb.ph0, qp[0], sa, 0, 0, 0);
            sb = __builtin_amdgcn_mfma_f32_32x32x16_bf16(kb.ph1, qp[1], sb, 0, 0, 0);
            sa = __builtin_amdgcn_mfma_f32_32x32x16_bf16(kb.ph2, qp[2], sa, 0, 0, 0);
            sb = __builtin_amdgcn_mfma_f32_32x32x16_bf16(kb.ph3, qp[3], sb, 0, 0, 0);
            sa = __builtin_amdgcn_mfma_f32_32x32x16_bf16(kb.ph4, qp[4], sa, 0, 0, 0);
            sb = __builtin_amdgcn_mfma_f32_32x32x16_bf16(kb.ph5, qp[5], sb, 0, 0, 0);
            sa = __builtin_amdgcn_mfma_f32_32x32x16_bf16(kb.ph6, qp[6], sa, 0, 0, 0);
            sb = __builtin_amdgcn_mfma_f32_32x32x16_bf16(kb.ph7, qp[7], sb, 0, 0, 0);
            float p[16];
            #pragma unroll
            for (int i = 0; i < 16; ++i) p[i] = sa[i] + sb[i];
            if (diag) {
                #pragma unroll
                for (int i = 0; i < 16; ++i) {
                    int kr = (i & 3) + 8 * (i >> 2) + 4 * hi;
                    if (kr > c31) p[i] = -1e30f;
                }
            }
            #pragma unroll
            for (int i = 0; i < 16; ++i) p[i] = __builtin_amdgcn_exp2f(p[i] - FMAXL2);
            float u4[4];
            #pragma unroll
            for (int i = 0; i < 4; ++i)
                u4[i] = (p[i] + p[i + 4]) + (p[i + 8] + p[i + 12]);
            l += (u4[0] + u4[1]) + (u4[2] + u4[3]);
            unsigned W[8];
            #pragma unroll
            for (int i = 0; i < 8; ++i) W[i] = cvtpk_bf16(p[2 * i], p[2 * i + 1]);
            union U16 { unsigned d[4]; bf16x8 v; };
#define PVSTEP(e, AV) { \
            unsigned x_  = W[4 * e],     y_  = W[4 * e + 2]; \
            unsigned x2_ = W[4 * e + 1], y2_ = W[4 * e + 3]; \
            asm volatile("v_permlane32_swap_b32 %0, %1" : "+v"(x_),  "+v"(y_)); \
            asm volatile("v_permlane32_swap_b32 %0, %1" : "+v"(x2_), "+v"(y2_)); \
            U16 pf; pf.d[0] = x_; pf.d[1] = x2_; pf.d[2] = y_; pf.d[3] = y2_; \
            acc = __builtin_amdgcn_mfma_f32_32x32x16_bf16(AV, pf.v, acc, 0, 0, 0); }
            PVSTEP(0, kb.vt0)
            PVSTEP(1, kb.vt1)
#undef PVSTEP
        };

        int t = tb;
        KB ka = LOADK(t);
        for (; t + 1 < te; ++t) {
            KB kn = LOADK(t + 1);
            PROCESS(ka, qa0, qa1, accA, lA, false);
            PROCESS(ka, qb0, qb1, accB, lB, false);
            ka = kn;
        }
        const bool dg = (t == r - 1);
        PROCESS(ka, qa0, qa1, accA, lA, dg);
        PROCESS(ka, qb0, qb1, accB, lB, dg);
    }

    // ---- emit partials for both heads ----
    {
        float* pa = pacc + (size_t)bid * 2048;
        #pragma unroll
        for (int k = 0; k < 4; ++k) {
            f32x4 v = {accA[4 * k], accA[4 * k + 1], accA[4 * k + 2], accA[4 * k + 3]};
            *(f32x4*)(pa + k * 256 + lane * 4) = v;
        }
        #pragma unroll
        for (int k = 0; k < 4; ++k) {
            f32x4 v = {accB[4 * k], accB[4 * k + 1], accB[4 * k + 2], accB[4 * k + 3]};
            *(f32x4*)(pa + 1024 + k * 256 + lane * 4) = v;
        }
        lA += __shfl_xor(lA, 32, 64);
        lB += __shfl_xor(lB, 32, 64);
        if (hi == 0) {
            pml[(size_t)bid * 64 + c31] = lA;
            pml[(size_t)bid * 64 + 32 + c31] = lB;
        }
    }
}

// ============================================================
// K2b: combine — R19-verbatim.
// ============================================================
__global__ __launch_bounds__(64) void combine_kernel(
    const float* __restrict__ pacc, const float* __restrict__ pml,
    unsigned short* __restrict__ Ob)
{
    const int lane = threadIdx.x & 63;
    const int hi = lane >> 5, c31 = lane & 31;
    const int bid = blockIdx.x;
    const int b = bid >> 9, h = (bid >> 6) & 7, s32 = bid & 63;
    const int kvh = h >> 1, hq = h & 1;
    const int grp = b * 4 + kvh;
    const int ubase = ((63 - s32) << 2);

    float L = 0.f;
    float o[16];
    #pragma unroll
    for (int i = 0; i < 16; ++i) o[i] = 0.f;
    #pragma unroll
    for (int i = 0; i < 4; ++i) {
        const int bidp = ((ubase | i) << 3) | grp;
        L += pml[(size_t)bidp * 64 + hq * 32 + c31];
        const float* pa = pacc + (size_t)bidp * 2048 + hq * 1024;
        #pragma unroll
        for (int k = 0; k < 4; ++k) {
            f32x4 v = *(const f32x4*)(pa + k * 256 + lane * 4);
            o[4 * k]     += v[0];
            o[4 * k + 1] += v[1];
            o[4 * k + 2] += v[2];
            o[4 * k + 3] += v[3];
        }
    }
    const float inv = 1.0f / L;

    unsigned short* ob = Ob + ((size_t)b * S_LEN + s32 * 32 + c31) * DMODEL + h * 24 + 4 * hi;
    #pragma unroll
    for (int k = 0; k < 3; ++k) {
        *(unsigned*)(ob + 8 * k)     = pk2(o[4 * k] * inv,     o[4 * k + 1] * inv);
        *(unsigned*)(ob + 8 * k + 2) = pk2(o[4 * k + 2] * inv, o[4 * k + 3] * inv);
    }
}

// ============================================================
// K3: proj — R19-verbatim.
// ============================================================
__global__ __launch_bounds__(256) void proj_gemm_kernel(
    const unsigned short* __restrict__ Ob, const float* __restrict__ Wo,
    float* __restrict__ out)
{
    __shared__ __align__(16) unsigned short a_lds[64][200];
    __shared__ __align__(16) unsigned short b_lds[64][200];
    const int tid = threadIdx.x;
    const int wid = tid >> 6, lane = tid & 63, g = lane >> 4, lr = lane & 15;
    const int brow = blockIdx.x * 64;
    const int bcol = blockIdx.y * 64;

    #pragma unroll
    for (int c = 0; c < 6; ++c) {
        int idx = c * 256 + tid;
        int r = idx / 24, ch = idx % 24;
        *(uint4*)&a_lds[r][ch * 8] = *(const uint4*)&Ob[(size_t)(brow + r) * 192 + ch * 8];
    }
    #pragma unroll
    for (int c = 0; c < 12; ++c) {
        int idx = c * 256 + tid;
        int r = idx / 48, ch = idx % 48;
        float4 wv = *(const float4*)&Wo[(size_t)(bcol + r) * 192 + ch * 4];
        uint2 w2; w2.x = pk2(wv.x, wv.y); w2.y = pk2(wv.z, wv.w);
        *(uint2*)&b_lds[r][ch * 4] = w2;
    }
    __syncthreads();

    f32x4 acc[4];
    #pragma unroll
    for (int nc = 0; nc < 4; ++nc) acc[nc] = (f32x4){0.f, 0.f, 0.f, 0.f};
    #pragma unroll
    for (int kc = 0; kc < 6; ++kc) {
        bf16x8 af = *(const bf16x8*)&a_lds[wid * 16 + lr][kc * 32 + g * 8];
        #pragma unroll
        for (int nc = 0; nc < 4; ++nc) {
            bf16x8 bfr = *(const bf16x8*)&b_lds[nc * 16 + lr][kc * 32 + g * 8];
            acc[nc] = __builtin_amdgcn_mfma_f32_16x16x32_bf16(af, bfr, acc[nc], 0, 0, 0);
        }
    }

    #pragma unroll
    for (int nc = 0; nc < 4; ++nc) {
        int c = bcol + nc * 16 + lr;
        #pragma unroll
        for (int r = 0; r < 4; ++r) {
            int row = brow + wid * 16 + g * 4 + r;
            out[(size_t)row * 192 + c] = acc[nc][r];
        }
    }
}

// ============================================================
extern "C" void kernel_launch(void* const* d_in, const int* in_sizes, int n_in,
                              void* d_out, int out_size, void* d_ws, size_t ws_size,
                              hipStream_t stream) {
    const float* x     = (const float*)d_in[0];
    const float* Wq    = (const float*)d_in[1];
    const float* Wkv   = (const float*)d_in[2];
    const float* Wo    = (const float*)d_in[3];
    const float* alpha = (const float*)d_in[4];
    const float* beta  = (const float*)d_in[5];

    char* ws = (char*)d_ws;
    const size_t QH_BYTES  = (size_t)B_N * 8 * S_LEN * 32 * 2;     // 2,097,152
    const size_t KF_BYTES  = (size_t)B_N * 4 * 65536 * 2;          // 1,048,576
    const size_t PHQ_BYTES = (size_t)B_N * S_LEN * 128 * 2;        // 1,048,576
    const size_t PHF_BYTES = (size_t)B_N * 262144 * 2;             // 1,048,576
    const size_t VF_BYTES  = KF_BYTES;                             // 1,048,576
    const size_t OB_BYTES  = (size_t)B_N * S_LEN * DMODEL * 2;     // 1,572,864
    const size_t PACC_BYTES = (size_t)2048 * 2048 * 4;             // 16,777,216

    unsigned short* Qh  = (unsigned short*)ws;
    unsigned short* Kf  = (unsigned short*)(ws + QH_BYTES);
    unsigned short* Phq = (unsigned short*)(ws + QH_BYTES + KF_BYTES);
    unsigned short* Phf = (unsigned short*)(ws + QH_BYTES + KF_BYTES + PHQ_BYTES);
    unsigned short* Vf  = (unsigned short*)(ws + QH_BYTES + KF_BYTES + PHQ_BYTES + PHF_BYTES);
    unsigned short* Ob  = (unsigned short*)(ws + QH_BYTES + KF_BYTES + PHQ_BYTES + PHF_BYTES + VF_BYTES);
    float* pacc = (float*)(ws + QH_BYTES + KF_BYTES + PHQ_BYTES + PHF_BYTES + VF_BYTES + OB_BYTES);
    float* pml  = (float*)(ws + QH_BYTES + KF_BYTES + PHQ_BYTES + PHF_BYTES + VF_BYTES + OB_BYTES + PACC_BYTES);
    float* out = (float*)d_out;

    // DIAGNOSTIC: prep launched twice (idempotent — identical inputs ->
    // identical outputs).  dur_us delta vs R19 = prep time + one gap.
    hipLaunchKernelGGL(prep_kernel, dim3(904), dim3(256), 0, stream,
                       x, Wq, Wkv, alpha, beta, Qh, Kf, Phq, Phf, Vf);
    hipLaunchKernelGGL(prep_kernel, dim3(904), dim3(256), 0, stream,
                       x, Wq, Wkv, alpha, beta, Qh, Kf, Phq, Phf, Vf);
    hipLaunchKernelGGL(attn_kernel, dim3(2048), dim3(64), 0, stream,
                       Qh, Kf, Phq, Phf, Vf, pacc, pml);
    hipLaunchKernelGGL(combine_kernel, dim3(1024), dim3(64), 0, stream,
                       pacc, pml, Ob);
    hipLaunchKernelGGL(proj_gemm_kernel, dim3(64, 3), dim3(256), 0, stream,
                       Ob, Wo, out);
}

// Round 21
// 40.155 us; speedup vs baseline: 1.1880x; 1.1880x over previous
//
#include <hip/hip_runtime.h>
#include <math.h>

// ---- problem constants ----
#define B_N    2
#define S_LEN  2048
#define DMODEL 192
#define LOG2E  1.44269504088896340736f
#define FMAXL2 12.0f   // fixed softmax max (log2 domain); scores bounded << this

typedef __attribute__((ext_vector_type(8)))  short bf16x8;
typedef __attribute__((ext_vector_type(4)))  float f32x4;
typedef __attribute__((ext_vector_type(16))) float f32x16;

static __device__ __forceinline__ unsigned short f2bf(float f) {
    union { float f; unsigned u; } v; v.f = f;
    unsigned r = v.u + 0x7FFFu + ((v.u >> 16) & 1u);
    return (unsigned short)(r >> 16);
}
static __device__ __forceinline__ unsigned pk2(float a, float b) {
    return (unsigned)f2bf(a) | ((unsigned)f2bf(b) << 16);
}
static __device__ __forceinline__ unsigned cvtpk_bf16(float a, float b) {
    unsigned r;
    asm("v_cvt_pk_bf16_f32 %0, %1, %2" : "=v"(r) : "v"(a), "v"(b));
    return r;
}

// Fragment-major layouts (all attn reads are base + lane*16B, 1KB/instr):
//  Kf [b][kvh][t][f:2][lane:64][8]  lane = key&31 | ((d>>3)&1)<<5, f = d>>4
//  Phf[b]     [t][f:8][lane:64][8]  lane = key&31 | ((d>>3)&1)<<5, f = d>>4
//  Vf [b][kvh][t][f:2][lane:64][8]  lane = d     | ((kr>>3)&1)<<5, f = kr>>4

// ============================================================
// K1: prep — R19-verbatim (passing).
// ============================================================
__global__ __launch_bounds__(256) void prep_kernel(
    const float* __restrict__ x, const float* __restrict__ Wq,
    const float* __restrict__ Wkv, const float* __restrict__ alpha_p,
    const float* __restrict__ beta_p,
    unsigned short* __restrict__ Qh, unsigned short* __restrict__ Kf,
    unsigned short* __restrict__ Phq, unsigned short* __restrict__ Phf,
    unsigned short* __restrict__ Vf)
{
    __shared__ __align__(16) unsigned short a_lds[64][200];
    __shared__ __align__(16) unsigned short b_lds[64][200];
    const int blk = blockIdx.x, tid = threadIdx.x;

    if (blk < 384) {
        const int wid = tid >> 6, lane = tid & 63, g = lane >> 4, lr = lane & 15;
        const int brow = (blk & 63) * 64;
        const int bcol = (blk >> 6) * 64;

        #pragma unroll
        for (int c = 0; c < 12; ++c) {
            int idx = c * 256 + tid;
            int r = idx / 48, ch = idx % 48;
            float4 v = *(const float4*)&x[(size_t)(brow + r) * 192 + ch * 4];
            uint2 w; w.x = pk2(v.x, v.y); w.y = pk2(v.z, v.w);
            *(uint2*)&a_lds[r][ch * 4] = w;
            int wr = bcol + r;
            const float* wsrc = (wr < 192) ? &Wq[(size_t)wr * 192 + ch * 4]
                                           : &Wkv[(size_t)(wr - 192) * 192 + ch * 4];
            float4 wv = *(const float4*)wsrc;
            uint2 w2; w2.x = pk2(wv.x, wv.y); w2.y = pk2(wv.z, wv.w);
            *(uint2*)&b_lds[r][ch * 4] = w2;
        }
        __syncthreads();

        f32x4 acc[4];
        #pragma unroll
        for (int nc = 0; nc < 4; ++nc) acc[nc] = (f32x4){0.f, 0.f, 0.f, 0.f};
        #pragma unroll
        for (int kc = 0; kc < 6; ++kc) {
            bf16x8 af = *(const bf16x8*)&a_lds[wid * 16 + lr][kc * 32 + g * 8];
            #pragma unroll
            for (int nc = 0; nc < 4; ++nc) {
                bf16x8 bfr = *(const bf16x8*)&b_lds[nc * 16 + lr][kc * 32 + g * 8];
                acc[nc] = __builtin_amdgcn_mfma_f32_16x16x32_bf16(af, bfr, acc[nc], 0, 0, 0);
            }
        }

        const float qs = alpha_p[0] * 0.20412414523193150818f * LOG2E;
        const float scale = (bcol < 192) ? qs : 1.0f;
        __syncthreads();
        unsigned short (*sm)[80] = (unsigned short (*)[80])&a_lds[0][0];
        #pragma unroll
        for (int nc = 0; nc < 4; ++nc)
            #pragma unroll
            for (int rr = 0; rr < 4; ++rr)
                sm[wid * 16 + g * 4 + rr][nc * 16 + lr] = f2bf(acc[nc][rr] * scale);
        __syncthreads();

        #pragma unroll
        for (int pass = 0; pass < 2; ++pass) {
            const int sp = pass * 256 + tid;
            if (bcol < 256) {
                const int cs = sp >> 6, row = sp & 63;
                const int grow = brow + row, b = grow >> 11, s = grow & 2047;
                uint4 v = *(const uint4*)&sm[row][cs * 8];
                const int col = bcol + cs * 8;
                if (bcol < 192) {
                    int h = col / 24, d = col - 24 * h;
                    *(uint4*)(Qh + ((size_t)(b * 8 + h) * S_LEN + s) * 32 + d) = v;
                } else {
                    int cc = col - 192, kvh = cc / 24, d = cc - 24 * kvh;
                    int t = s >> 5, kr = s & 31;
                    *(uint4*)(Kf + (((size_t)(b * 4 + kvh) * 64 + t) * 2 + (d >> 4)) * 512
                              + (kr + 32 * ((d >> 3) & 1)) * 8) = v;
                }
            } else if (bcol == 256) {
                if (sp < 256) {
                    const int cs = sp >> 6, row = sp & 63;
                    const int grow = brow + row, b = grow >> 11, s = grow & 2047;
                    uint4 v = *(const uint4*)&sm[row][cs * 8];
                    const int col = 256 + cs * 8;
                    int cc = col - 192, kvh = cc / 24, d = cc - 24 * kvh;
                    int t = s >> 5, kr = s & 31;
                    *(uint4*)(Kf + (((size_t)(b * 4 + kvh) * 64 + t) * 2 + (d >> 4)) * 512
                              + (kr + 32 * ((d >> 3) & 1)) * 8) = v;
                } else {
                    const int sp2 = sp - 256;
                    const int colL = 32 + (sp2 & 31), r0 = (sp2 >> 5) * 8;
                    const int grow0 = brow + r0, b = grow0 >> 11, s0 = grow0 & 2047;
                    const int col = 256 + colL;
                    int cc = col - 288, kvh = cc / 24, d = cc - 24 * kvh;
                    int t = s0 >> 5, kr0 = s0 & 31;
                    unsigned w0 = (unsigned)sm[r0][colL]     | ((unsigned)sm[r0 + 1][colL] << 16);
                    unsigned w1 = (unsigned)sm[r0 + 2][colL] | ((unsigned)sm[r0 + 3][colL] << 16);
                    unsigned w2 = (unsigned)sm[r0 + 4][colL] | ((unsigned)sm[r0 + 5][colL] << 16);
                    unsigned w3 = (unsigned)sm[r0 + 6][colL] | ((unsigned)sm[r0 + 7][colL] << 16);
                    uint4 v = {w0, w1, w2, w3};
                    *(uint4*)(Vf + (((size_t)(b * 4 + kvh) * 64 + t) * 2 + (kr0 >> 4)) * 512
                              + (d + 32 * ((kr0 >> 3) & 1)) * 8) = v;
                }
            } else {
                const int colL = sp & 63, r0 = (sp >> 6) * 8;
                const int grow0 = brow + r0, b = grow0 >> 11, s0 = grow0 & 2047;
                const int col = 320 + colL;
                int cc = col - 288, kvh = cc / 24, d = cc - 24 * kvh;
                int t = s0 >> 5, kr0 = s0 & 31;
                unsigned w0 = (unsigned)sm[r0][colL]     | ((unsigned)sm[r0 + 1][colL] << 16);
                unsigned w1 = (unsigned)sm[r0 + 2][colL] | ((unsigned)sm[r0 + 3][colL] << 16);
                unsigned w2 = (unsigned)sm[r0 + 4][colL] | ((unsigned)sm[r0 + 5][colL] << 16);
                unsigned w3 = (unsigned)sm[r0 + 6][colL] | ((unsigned)sm[r0 + 7][colL] << 16);
                uint4 v = {w0, w1, w2, w3};
                *(uint4*)(Vf + (((size_t)(b * 4 + kvh) * 64 + t) * 2 + (kr0 >> 4)) * 512
                          + (d + 32 * ((kr0 >> 3) & 1)) * 8) = v;
            }
        }
    } else if (blk < 896) {
        unsigned short (*psm)[128] = (unsigned short (*)[128])&a_lds[0][0];
        const int pblk = blk - 384;
        const int rr = tid >> 5, i = tid & 31;
        const int row = pblk * 8 + rr;
        const int b = row >> 11, s = row & 2047;
        const int t = s >> 5, kr = s & 31;
        const float bf = beta_p[0] * (1.0f / 64.0f) * LOG2E;
        float2 p = *(const float2*)&x[(size_t)row * DMODEL + 128 + 2 * i];
        float s0, c0, s1, c1;
        sincosf(p.x, &s0, &c0);
        sincosf(p.y, &s1, &c1);
        unsigned short* phq = Phq + ((size_t)b * S_LEN + s) * 128;
        *(unsigned*)(phq + 2 * i)      = pk2(c0 * bf, c1 * bf);
        *(unsigned*)(phq + 64 + 2 * i) = pk2(s0 * bf, s1 * bf);
        *(unsigned*)&psm[rr][2 * i]      = pk2(c0, c1);
        *(unsigned*)&psm[rr][64 + 2 * i] = pk2(s0, s1);
        if (i < 12) {
            uint4 z = {0u, 0u, 0u, 0u};
            if (i < 8) {
                *(uint4*)(Qh + ((size_t)(b * 8 + i) * S_LEN + s) * 32 + 24) = z;
            } else {
                int kvh = i - 8;
                *(uint4*)(Kf + (((size_t)(b * 4 + kvh) * 64 + t) * 2 + 1) * 512 + (kr + 32) * 8) = z;
            }
        }
        __syncthreads();
        if (tid < 128) {
            const int krow = tid & 7, d0 = (tid >> 3) * 8;
            const int grow = pblk * 8 + krow, b2 = grow >> 11, s2 = grow & 2047;
            const int t2 = s2 >> 5, kr2 = s2 & 31;
            uint4 v = *(const uint4*)&psm[krow][d0];
            *(uint4*)(Phf + (((size_t)b2 * 64 + t2) * 8 + (d0 >> 4)) * 512
                      + (kr2 + 32 * ((d0 >> 3) & 1)) * 8) = v;
        }
    } else {
        const int j = blk - 896;
        uint4 z = {0u, 0u, 0u, 0u};
        #pragma unroll
        for (int c = 0; c < 8; ++c) {
            int idx = c * 256 + tid;
            int t = idx >> 5, rem = idx & 31;
            int f = rem >> 4, dd = 24 + (rem & 7), hb = (rem >> 3) & 1;
            *(uint4*)(Vf + (((size_t)j * 64 + t) * 2 + f) * 512 + (dd + 32 * hb) * 8) = z;
        }
    }
}

// ============================================================
// K2: 4-way key-split attention — R19-verbatim.
// ============================================================
struct KB { bf16x8 kh0, kh1, ph0, ph1, ph2, ph3, ph4, ph5, ph6, ph7, vt0, vt1; };

__global__ __launch_bounds__(64, 2) void attn_kernel(
    const unsigned short* __restrict__ Qh, const unsigned short* __restrict__ Kf,
    const unsigned short* __restrict__ Phq, const unsigned short* __restrict__ Phf,
    const unsigned short* __restrict__ Vf,
    float* __restrict__ pacc, float* __restrict__ pml)
{
    const int lane = threadIdx.x & 63;
    const int hi = lane >> 5, c31 = lane & 31;

    const int bid = blockIdx.x;
    const int grp = bid & 7, b = grp >> 2, kvh = grp & 3;
    const int u = bid >> 3;
    const int quarter = u & 3;
    const int s = 63 - (u >> 2);
    const int r = s + 1;
    const int tb = (quarter * r) >> 2, te = ((quarter + 1) * r) >> 2;
    const int qrow = s * 32 + c31;

    const unsigned short* kf_g = Kf  + (size_t)(b * 4 + kvh) * 65536 + lane * 8;
    const unsigned short* ph_g = Phf + (size_t)b * 262144 + lane * 8;
    const unsigned short* vf_g = Vf  + (size_t)(b * 4 + kvh) * 65536 + lane * 8;

    f32x16 accA = {0,0,0,0,0,0,0,0,0,0,0,0,0,0,0,0};
    f32x16 accB = {0,0,0,0,0,0,0,0,0,0,0,0,0,0,0,0};
    float lA = 0.f, lB = 0.f;

    if (te > tb) {
        bf16x8 qa0, qa1, qb0, qb1, qp[8];
        {
            const unsigned short* q0 = Qh + ((size_t)(b * 8 + 2 * kvh) * S_LEN + qrow) * 32 + hi * 8;
            const unsigned short* q1 = Qh + ((size_t)(b * 8 + 2 * kvh + 1) * S_LEN + qrow) * 32 + hi * 8;
            qa0 = *(const bf16x8*)q0; qa1 = *(const bf16x8*)(q0 + 16);
            qb0 = *(const bf16x8*)q1; qb1 = *(const bf16x8*)(q1 + 16);
            const unsigned short* pq = Phq + ((size_t)b * S_LEN + qrow) * 128 + hi * 8;
            #pragma unroll
            for (int c = 0; c < 8; ++c) qp[c] = *(const bf16x8*)(pq + c * 16);
        }

        auto LOADK = [&](int t) {
            KB kb;
            const unsigned short* kg = kf_g + (size_t)t * 1024;
            const unsigned short* pg = ph_g + (size_t)t * 4096;
            const unsigned short* vg = vf_g + (size_t)t * 1024;
            kb.kh0 = *(const bf16x8*)kg;
            kb.kh1 = *(const bf16x8*)(kg + 512);
            kb.ph0 = *(const bf16x8*)pg;
            kb.ph1 = *(const bf16x8*)(pg + 512);
            kb.ph2 = *(const bf16x8*)(pg + 1024);
            kb.ph3 = *(const bf16x8*)(pg + 1536);
            kb.ph4 = *(const bf16x8*)(pg + 2048);
            kb.ph5 = *(const bf16x8*)(pg + 2560);
            kb.ph6 = *(const bf16x8*)(pg + 3072);
            kb.ph7 = *(const bf16x8*)(pg + 3584);
            kb.vt0 = *(const bf16x8*)vg;
            kb.vt1 = *(const bf16x8*)(vg + 512);
            return kb;
        };

        auto PROCESS = [&](const KB& kb, bf16x8 q0, bf16x8 q1,
                           f32x16& acc, float& l, bool diag) {
            f32x16 sa = {0,0,0,0,0,0,0,0,0,0,0,0,0,0,0,0};
            f32x16 sb = {0,0,0,0,0,0,0,0,0,0,0,0,0,0,0,0};
            sa = __builtin_amdgcn_mfma_f32_32x32x16_bf16(kb.kh0, q0, sa, 0, 0, 0);
            sb = __builtin_amdgcn_mfma_f32_32x32x16_bf16(kb.kh1, q1, sb, 0, 0, 0);
            sa = __builtin_amdgcn_mfma_f32_32x32x16_bf16(kb.ph0, qp[0], sa, 0, 0, 0);
            sb = __builtin_amdgcn_mfma_f32_32x32x16_bf16(kb.ph1, qp[1], sb, 0, 0, 0);
            sa = __builtin_amdgcn_mfma_f32_32x32x16_bf16(kb.ph2, qp[2], sa, 0, 0, 0);
            sb = __builtin_amdgcn_mfma_f32_32x32x16_bf16(kb.ph3, qp[3], sb, 0, 0, 0);
            sa = __builtin_amdgcn_mfma_f32_32x32x16_bf16(kb.ph4, qp[4], sa, 0, 0, 0);
            sb = __builtin_amdgcn_mfma_f32_32x32x16_bf16(kb.ph5, qp[5], sb, 0, 0, 0);
            sa = __builtin_amdgcn_mfma_f32_32x32x16_bf16(kb.ph6, qp[6], sa, 0, 0, 0);
            sb = __builtin_amdgcn_mfma_f32_32x32x16_bf16(kb.ph7, qp[7], sb, 0, 0, 0);
            float p[16];
            #pragma unroll
            for (int i = 0; i < 16; ++i) p[i] = sa[i] + sb[i];
            if (diag) {
                #pragma unroll
                for (int i = 0; i < 16; ++i) {
                    int kr = (i & 3) + 8 * (i >> 2) + 4 * hi;
                    if (kr > c31) p[i] = -1e30f;
                }
            }
            #pragma unroll
            for (int i = 0; i < 16; ++i) p[i] = __builtin_amdgcn_exp2f(p[i] - FMAXL2);
            float u4[4];
            #pragma unroll
            for (int i = 0; i < 4; ++i)
                u4[i] = (p[i] + p[i + 4]) + (p[i + 8] + p[i + 12]);
            l += (u4[0] + u4[1]) + (u4[2] + u4[3]);
            unsigned W[8];
            #pragma unroll
            for (int i = 0; i < 8; ++i) W[i] = cvtpk_bf16(p[2 * i], p[2 * i + 1]);
            union U16 { unsigned d[4]; bf16x8 v; };
#define PVSTEP(e, AV) { \
            unsigned x_  = W[4 * e],     y_  = W[4 * e + 2]; \
            unsigned x2_ = W[4 * e + 1], y2_ = W[4 * e + 3]; \
            asm volatile("v_permlane32_swap_b32 %0, %1" : "+v"(x_),  "+v"(y_)); \
            asm volatile("v_permlane32_swap_b32 %0, %1" : "+v"(x2_), "+v"(y2_)); \
            U16 pf; pf.d[0] = x_; pf.d[1] = x2_; pf.d[2] = y_; pf.d[3] = y2_; \
            acc = __builtin_amdgcn_mfma_f32_32x32x16_bf16(AV, pf.v, acc, 0, 0, 0); }
            PVSTEP(0, kb.vt0)
            PVSTEP(1, kb.vt1)
#undef PVSTEP
        };

        int t = tb;
        KB ka = LOADK(t);
        for (; t + 1 < te; ++t) {
            KB kn = LOADK(t + 1);
            PROCESS(ka, qa0, qa1, accA, lA, false);
            PROCESS(ka, qb0, qb1, accB, lB, false);
            ka = kn;
        }
        const bool dg = (t == r - 1);
        PROCESS(ka, qa0, qa1, accA, lA, dg);
        PROCESS(ka, qb0, qb1, accB, lB, dg);
    }

    // ---- emit partials for both heads ----
    {
        float* pa = pacc + (size_t)bid * 2048;
        #pragma unroll
        for (int k = 0; k < 4; ++k) {
            f32x4 v = {accA[4 * k], accA[4 * k + 1], accA[4 * k + 2], accA[4 * k + 3]};
            *(f32x4*)(pa + k * 256 + lane * 4) = v;
        }
        #pragma unroll
        for (int k = 0; k < 4; ++k) {
            f32x4 v = {accB[4 * k], accB[4 * k + 1], accB[4 * k + 2], accB[4 * k + 3]};
            *(f32x4*)(pa + 1024 + k * 256 + lane * 4) = v;
        }
        lA += __shfl_xor(lA, 32, 64);
        lB += __shfl_xor(lB, 32, 64);
        if (hi == 0) {
            pml[(size_t)bid * 64 + c31] = lA;
            pml[(size_t)bid * 64 + 32 + c31] = lB;
        }
    }
}

// ============================================================
// K3: FUSED combine + proj.  Grid (64, 3) x 256 threads.
// Phase 1: compute the 64 Ob rows this block needs (16 combine
// units = 2 s32-groups x 8 heads; 4 units per 64-lane group,
// looped x4) directly from pacc/pml into a_lds (combine formulas
// R19-verbatim; lane semantic identical).  Phase 2: R19 proj GEMM
// reading A from a_lds (B = Wo f32->bf16 staged as before).
// ============================================================
__global__ __launch_bounds__(256) void combine_proj_kernel(
    const float* __restrict__ pacc, const float* __restrict__ pml,
    const float* __restrict__ Wo, float* __restrict__ out)
{
    __shared__ __align__(16) unsigned short a_lds[64][200];
    __shared__ __align__(16) unsigned short b_lds[64][200];
    const int tid = threadIdx.x;
    const int brow = blockIdx.x * 64;
    const int bcol = blockIdx.y * 64;
    const int b = brow >> 11;
    const int s32base = (brow & 2047) >> 5;     // first of 2 s32-groups

    // ---- stage B (Wo f32 -> bf16), independent of phase 1 ----
    #pragma unroll
    for (int c = 0; c < 12; ++c) {
        int idx = c * 256 + tid;
        int rr = idx / 48, ch = idx % 48;
        float4 wv = *(const float4*)&Wo[(size_t)(bcol + rr) * 192 + ch * 4];
        uint2 w2; w2.x = pk2(wv.x, wv.y); w2.y = pk2(wv.z, wv.w);
        *(uint2*)&b_lds[rr][ch * 4] = w2;
    }

    // ---- phase 1: combine 16 units into a_lds ----
    {
        const int lane = tid & 63;
        const int hi = lane >> 5, c31 = lane & 31;
        #pragma unroll
        for (int g4 = 0; g4 < 4; ++g4) {
            const int uu = g4 * 4 + (tid >> 6);      // unit 0..15
            const int s32off = uu & 1, h = uu >> 1;
            const int s32 = s32base + s32off;
            const int kvh = h >> 1, hq = h & 1;
            const int grp = b * 4 + kvh;
            const int ubase = ((63 - s32) << 2);

            float L = 0.f;
            float o[16];
            #pragma unroll
            for (int i = 0; i < 16; ++i) o[i] = 0.f;
            #pragma unroll
            for (int i = 0; i < 4; ++i) {
                const int bidp = ((ubase | i) << 3) | grp;
                L += pml[(size_t)bidp * 64 + hq * 32 + c31];
                const float* pa = pacc + (size_t)bidp * 2048 + hq * 1024;
                #pragma unroll
                for (int k = 0; k < 4; ++k) {
                    f32x4 v = *(const f32x4*)(pa + k * 256 + lane * 4);
                    o[4 * k]     += v[0];
                    o[4 * k + 1] += v[1];
                    o[4 * k + 2] += v[2];
                    o[4 * k + 3] += v[3];
                }
            }
            const float inv = 1.0f / L;
            unsigned short* ob = &a_lds[s32off * 32 + c31][h * 24 + 4 * hi];
            #pragma unroll
            for (int k = 0; k < 3; ++k) {
                *(unsigned*)(ob + 8 * k)     = pk2(o[4 * k] * inv,     o[4 * k + 1] * inv);
                *(unsigned*)(ob + 8 * k + 2) = pk2(o[4 * k + 2] * inv, o[4 * k + 3] * inv);
            }
        }
    }
    __syncthreads();

    // ---- phase 2: GEMM (R19 proj-verbatim, A from a_lds) ----
    const int wid = tid >> 6, lane = tid & 63, g = lane >> 4, lr = lane & 15;
    f32x4 acc[4];
    #pragma unroll
    for (int nc = 0; nc < 4; ++nc) acc[nc] = (f32x4){0.f, 0.f, 0.f, 0.f};
    #pragma unroll
    for (int kc = 0; kc < 6; ++kc) {
        bf16x8 af = *(const bf16x8*)&a_lds[wid * 16 + lr][kc * 32 + g * 8];
        #pragma unroll
        for (int nc = 0; nc < 4; ++nc) {
            bf16x8 bfr = *(const bf16x8*)&b_lds[nc * 16 + lr][kc * 32 + g * 8];
            acc[nc] = __builtin_amdgcn_mfma_f32_16x16x32_bf16(af, bfr, acc[nc], 0, 0, 0);
        }
    }

    #pragma unroll
    for (int nc = 0; nc < 4; ++nc) {
        int c = bcol + nc * 16 + lr;
        #pragma unroll
        for (int r = 0; r < 4; ++r) {
            int row = brow + wid * 16 + g * 4 + r;
            out[(size_t)row * 192 + c] = acc[nc][r];
        }
    }
}

// ============================================================
extern "C" void kernel_launch(void* const* d_in, const int* in_sizes, int n_in,
                              void* d_out, int out_size, void* d_ws, size_t ws_size,
                              hipStream_t stream) {
    const float* x     = (const float*)d_in[0];
    const float* Wq    = (const float*)d_in[1];
    const float* Wkv   = (const float*)d_in[2];
    const float* Wo    = (const float*)d_in[3];
    const float* alpha = (const float*)d_in[4];
    const float* beta  = (const float*)d_in[5];

    char* ws = (char*)d_ws;
    const size_t QH_BYTES  = (size_t)B_N * 8 * S_LEN * 32 * 2;     // 2,097,152
    const size_t KF_BYTES  = (size_t)B_N * 4 * 65536 * 2;          // 1,048,576
    const size_t PHQ_BYTES = (size_t)B_N * S_LEN * 128 * 2;        // 1,048,576
    const size_t PHF_BYTES = (size_t)B_N * 262144 * 2;             // 1,048,576
    const size_t VF_BYTES  = KF_BYTES;                             // 1,048,576
    const size_t OB_BYTES  = (size_t)B_N * S_LEN * DMODEL * 2;     // 1,572,864 (unused; layout kept)
    const size_t PACC_BYTES = (size_t)2048 * 2048 * 4;             // 16,777,216

    unsigned short* Qh  = (unsigned short*)ws;
    unsigned short* Kf  = (unsigned short*)(ws + QH_BYTES);
    unsigned short* Phq = (unsigned short*)(ws + QH_BYTES + KF_BYTES);
    unsigned short* Phf = (unsigned short*)(ws + QH_BYTES + KF_BYTES + PHQ_BYTES);
    unsigned short* Vf  = (unsigned short*)(ws + QH_BYTES + KF_BYTES + PHQ_BYTES + PHF_BYTES);
    float* pacc = (float*)(ws + QH_BYTES + KF_BYTES + PHQ_BYTES + PHF_BYTES + VF_BYTES + OB_BYTES);
    float* pml  = (float*)(ws + QH_BYTES + KF_BYTES + PHQ_BYTES + PHF_BYTES + VF_BYTES + OB_BYTES + PACC_BYTES);
    float* out = (float*)d_out;

    hipLaunchKernelGGL(prep_kernel, dim3(904), dim3(256), 0, stream,
                       x, Wq, Wkv, alpha, beta, Qh, Kf, Phq, Phf, Vf);
    hipLaunchKernelGGL(attn_kernel, dim3(2048), dim3(64), 0, stream,
                       Qh, Kf, Phq, Phf, Vf, pacc, pml);
    hipLaunchKernelGGL(combine_proj_kernel, dim3(64, 3), dim3(256), 0, stream,
                       pacc, pml, Wo, out);
}